// Round 5
// baseline (448.365 us; speedup 1.0000x reference)
//
#include <hip/hip_runtime.h>
#include <hip/hip_fp16.h>

typedef _Float16 half8 __attribute__((ext_vector_type(8)));
typedef float f32x4 __attribute__((ext_vector_type(4)));

__device__ __forceinline__ float tanh_fast(float x) {
  float e = __expf(2.0f * x);
  return 1.0f - 2.0f / (e + 1.0f);
}

__device__ __forceinline__ void gload16(const _Float16* g, _Float16* l) {
  __builtin_amdgcn_global_load_lds((const __attribute__((address_space(1))) void*)g,
                                   (__attribute__((address_space(3))) void*)l,
                                   16, 0, 0);
}

// ---------------- transpose input_v [64][2048][196] f32 -> Vt [64][196][2048] fp16
__global__ __launch_bounds__(256) void k_transpose_v(const float* __restrict__ in,
                                                     _Float16* __restrict__ out) {
  __shared__ float t[64][65];
  int b = blockIdx.z;
  int c0 = blockIdx.y * 64;
  int p0 = blockIdx.x * 64;
  int tid = threadIdx.x;
  int pl = tid & 63;
  #pragma unroll
  for (int s = 0; s < 16; ++s) {
    int cl = (tid >> 6) + s * 4;
    int p = p0 + pl;
    t[cl][pl] = (p < 196) ? in[((size_t)b * 2048 + (c0 + cl)) * 196 + p] : 0.0f;
  }
  __syncthreads();
  int c8 = (tid & 7) * 8;
  #pragma unroll
  for (int s = 0; s < 2; ++s) {
    int p = p0 + (tid >> 3) + s * 32;
    if (p < 196) {
      half8 v;
      #pragma unroll
      for (int j = 0; j < 8; ++j) v[j] = (_Float16)t[c8 + j][(tid >> 3) + s * 32];
      *(half8*)(out + ((size_t)b * 196 + p) * 2048 + c0 + c8) = v;
    }
  }
}

// ---------------- prep: Wv_att f32 -> fp16 padded to 1280 rows; wgt init with batt
__global__ __launch_bounds__(256) void k_prep(const float* __restrict__ W,
                                              _Float16* __restrict__ Wh,
                                              const float* __restrict__ batt,
                                              float* __restrict__ wgt) {
  int i = blockIdx.x * 256 + threadIdx.x;  // < 1280*2048
  int n = i >> 11;
  Wh[i] = (n < 1200) ? (_Float16)W[i] : (_Float16)0.0f;
  if (i < 25088) wgt[i] = batt[(i / 196) & 1];
}

// ---------------- big MFMA GEMM v6: 256x256 tile, BK=64, 8 waves, 8-phase schedule.
// v5->v6: fix the flat-load regression. v5's char*-based LDS pointers defeated
// address-space inference -> flat loads (phase 1700->2900cyc, MfmaUtil 29->17).
// v6 keeps the zero-VALU immediate-offset scheme but roots every access in the
// shared array itself: lane-constant int indices (row&7==fr&7 -> swizzle term
// is lane-constant) + compile-time buf/mh/mt offsets folded into the ds_read
// offset immediate. Guaranteed ds_read_b128, one base VGPR per kk.
// Schedule unchanged (8-phase, vmcnt(6) gates at ph4/ph8, lgkmcnt(0) drains).
// Bijective XCD swizzle retained. Fused epilogue (array-free).
__global__ __launch_bounds__(512, 2) void k_gemm1(const _Float16* __restrict__ A,
                                                  const _Float16* __restrict__ B,
                                                  const float* __restrict__ bias,
                                                  const float* __restrict__ xq,
                                                  const float* __restrict__ Watt,
                                                  float* __restrict__ wgt) {
  __shared__ __align__(16) _Float16 AS[2][256 * 64];
  __shared__ __align__(16) _Float16 BS[2][256 * 64];
  int tid = threadIdx.x;
  // bijective XCD swizzle: 245 wgs, 8 XCDs -> q=30, r=5
  int lin = blockIdx.y * 5 + blockIdx.x;
  int xcd = lin & 7;
  int loc = lin >> 3;
  int nw = (xcd < 5 ? xcd * 31 : 155 + (xcd - 5) * 30) + loc;
  int n0 = (nw % 5) * 256;     // 5 n-tiles (padded N=1280)
  int m0 = (nw / 5) * 256;     // 49 m-tiles, exact
  int lane = tid & 63;
  int wave = tid >> 6;
  int wm = (wave >> 2) * 128;  // 2 wave rows
  int wn = (wave & 3) * 64;    // 4 wave cols
  int fr = lane & 15;
  int fq = lane >> 4;

  // ---- ds_read lane indices (halfs): idx = row*64 + ((kk*4+fq)^(fr&7))*8,
  // with row = (wm|wn) + fr (row&7 == fr&7, so the XOR term is lane-constant).
  // buf/mh/mt/nh/nt offsets are compile-time and fold into the ds offset field.
  int aIdx[2], bIdx[2];
  #pragma unroll
  for (int kk = 0; kk < 2; ++kk) {
    int sw = (((kk * 4 + fq) ^ (fr & 7)) << 3);
    aIdx[kk] = (wm + fr) * 64 + sw;
    bIdx[kk] = (wn + fr) * 64 + sw;
  }

  // ---- staging addressing: instr (h,j) covers 64 rows x 8 chunks; lane ->
  // row += lane>>3, chunk (lane&7) swizzled by row&7 (= lane>>3).
  int lr = lane >> 3;
  int swz8 = ((lane & 7) ^ lr) << 3;
  const _Float16* aSrc[2][2];
  const _Float16* bSrc[2][2];
  int aDst[2][2], bDst[2][2];
  #pragma unroll
  for (int h = 0; h < 2; ++h)
    #pragma unroll
    for (int j = 0; j < 2; ++j) {
      int ra = j * 128 + h * 64 + wave * 8;                  // A block-row
      aSrc[h][j] = A + (size_t)(m0 + ra + lr) * 2048 + swz8;
      aDst[h][j] = ra * 64;
      int rb = (j * 2 + (wave >> 2)) * 64 + h * 32 + (wave & 3) * 8;  // B block-row
      bSrc[h][j] = B + (size_t)(n0 + rb + lr) * 2048 + swz8;
      bDst[h][j] = rb * 64;
    }

  f32x4 acc[8][4];
  #pragma unroll
  for (int i = 0; i < 8; ++i)
    #pragma unroll
    for (int j = 0; j < 4; ++j) acc[i][j] = (f32x4){0.f, 0.f, 0.f, 0.f};

  // off = compile-time halfs offset relative to current iteration base
  auto stA = [&](int buf, int h, int off) {
    gload16(aSrc[h][0] + off, &AS[buf][aDst[h][0]]);
    gload16(aSrc[h][1] + off, &AS[buf][aDst[h][1]]);
  };
  auto stB = [&](int buf, int h, int off) {
    gload16(bSrc[h][0] + off, &BS[buf][bDst[h][0]]);
    gload16(bSrc[h][1] + off, &BS[buf][bDst[h][1]]);
  };
  auto dsA = [&](int buf, int mh, half8 (&a)[4][2]) {
    #pragma unroll
    for (int mt = 0; mt < 4; ++mt)
      #pragma unroll
      for (int kk = 0; kk < 2; ++kk)
        a[mt][kk] = *(const half8*)&AS[0][aIdx[kk] + (buf * 16384 + mh * 4096 + mt * 1024)];
  };
  auto dsB = [&](int buf, int nh, half8 (&b)[2][2]) {
    #pragma unroll
    for (int nt = 0; nt < 2; ++nt)
      #pragma unroll
      for (int kk = 0; kk < 2; ++kk)
        b[nt][kk] = *(const half8*)&BS[0][bIdx[kk] + (buf * 16384 + nh * 2048 + nt * 1024)];
  };
  auto mma = [&](half8 (&a)[4][2], half8 (&b)[2][2], int mh, int nh) {
    __builtin_amdgcn_s_setprio(1);
    #pragma unroll
    for (int kk = 0; kk < 2; ++kk)          // kk outermost: 8 independent MFMAs
      #pragma unroll
      for (int mt = 0; mt < 4; ++mt)
        #pragma unroll
        for (int nt = 0; nt < 2; ++nt)
          acc[mh * 4 + mt][nh * 2 + nt] = __builtin_amdgcn_mfma_f32_16x16x32_f16(
              a[mt][kk], b[nt][kk], acc[mh * 4 + mt][nh * 2 + nt], 0, 0, 0);
    __builtin_amdgcn_s_setprio(0);
  };

#define BAR() __builtin_amdgcn_s_barrier()
#define FENCE() asm volatile("" ::: "memory")
#define LGKM0() asm volatile("s_waitcnt lgkmcnt(0)")
#define LGKM8() asm volatile("s_waitcnt lgkmcnt(8)")

  // prologue: tile0 -> buf0 complete (oldest 8), tile1 -> buf1 {Aa,B0,B1} (6)
  stA(0, 0, 0); stB(0, 0, 0); stB(0, 1, 0); stA(0, 1, 0);
  stA(1, 0, 64); stB(1, 0, 64); stB(1, 1, 64);
  asm volatile("s_waitcnt vmcnt(6)" ::: "memory");
  BAR();
  FENCE();

  half8 a[4][2], b0[2][2], b1[2][2];
  for (int i = 0; i < 16; ++i) {
    const bool nl = (i < 15);
    // ---- ph1: Q(mh0,nh0) buf0 | stage buf1.Abeta (tile 2i+1)
    dsA(0, 0, a); dsB(0, 0, b0);
    stA(1, 1, 64);
    LGKM8();
    BAR(); LGKM0();
    mma(a, b0, 0, 0);
    BAR();
    // ---- ph2: Q(mh0,nh1) | stage buf0.Aalpha (tile 2i+2)
    dsB(0, 1, b1);
    if (nl) stA(0, 0, 128);
    BAR(); LGKM0();
    mma(a, b1, 0, 1);
    BAR();
    // ---- ph3: Q(mh1,nh1) | stage buf0.B0
    dsA(0, 1, a);
    if (nl) stB(0, 0, 128);
    BAR(); LGKM0();
    mma(a, b1, 1, 1);
    BAR();
    // ---- ph4: Q(mh1,nh0) (b0 from regs) | stage buf0.B1 | vmcnt gate for buf1
    if (nl) {
      stB(0, 1, 128);
      asm volatile("s_waitcnt vmcnt(6)" ::: "memory");
    } else {
      asm volatile("s_waitcnt vmcnt(0)" ::: "memory");
    }
    BAR();
    FENCE();
    mma(a, b0, 1, 0);
    BAR();
    // ---- ph5: Q(mh0,nh0) buf1 | stage buf0.Abeta
    dsA(1, 0, a); dsB(1, 0, b0);
    if (nl) stA(0, 1, 128);
    LGKM8();
    BAR(); LGKM0();
    mma(a, b0, 0, 0);
    BAR();
    // ---- ph6: Q(mh0,nh1) | stage buf1.Aalpha (tile 2i+3)
    dsB(1, 1, b1);
    if (nl) stA(1, 0, 192);
    BAR(); LGKM0();
    mma(a, b1, 0, 1);
    BAR();
    // ---- ph7: Q(mh1,nh1) | stage buf1.B0
    dsA(1, 1, a);
    if (nl) stB(1, 0, 192);
    BAR(); LGKM0();
    mma(a, b1, 1, 1);
    BAR();
    // ---- ph8: Q(mh1,nh0) | stage buf1.B1 | vmcnt gate for buf0
    if (nl) {
      stB(1, 1, 192);
      asm volatile("s_waitcnt vmcnt(6)" ::: "memory");
    }
    BAR();
    FENCE();
    mma(a, b0, 1, 0);
    BAR();
    // ---- advance staging pointers by 2 K-tiles (128 halfs)
    #pragma unroll
    for (int h = 0; h < 2; ++h)
      #pragma unroll
      for (int j = 0; j < 2; ++j) { aSrc[h][j] += 128; bSrc[h][j] += 128; }
  }
#undef BAR
#undef FENCE
#undef LGKM0
#undef LGKM8

  // ---- fused epilogue (array-free): xa = tanh(tanh(acc+bias)*xq); wgt += xa*Watt
  float bcol[4], wa0c[4], wa1c[4], xqv[4];
  int colv[4]; bool okv[4];
  #pragma unroll
  for (int nf = 0; nf < 4; ++nf) {
    int col = n0 + wn + (nf >> 1) * 32 + (nf & 1) * 16 + fr;
    bool ok = col < 1200;
    colv[nf] = col; okv[nf] = ok;
    bcol[nf] = ok ? bias[col] : 0.f;
    wa0c[nf] = ok ? Watt[col] : 0.f;
    wa1c[nf] = ok ? Watt[1200 + col] : 0.f;
    xqv[nf] = 0.f;
  }
  int bprev = -1;
  #pragma unroll
  for (int mf = 0; mf < 8; ++mf) {
    #pragma unroll
    for (int r = 0; r < 4; ++r) {
      int row = m0 + wm + (mf >> 2) * 64 + (mf & 3) * 16 + fq * 4 + r;
      int b = row / 196;
      if (b != bprev) {
        bprev = b;
        #pragma unroll
        for (int nf = 0; nf < 4; ++nf)
          xqv[nf] = okv[nf] ? xq[b * 1200 + colv[nf]] : 0.f;
      }
      float t0 = 0.f, t1 = 0.f;
      #pragma unroll
      for (int nf = 0; nf < 4; ++nf) {
        float xv = tanh_fast(acc[mf][nf][r] + bcol[nf]);
        float xa = tanh_fast(xv * xqv[nf]);
        t0 += xa * wa0c[nf];
        t1 += xa * wa1c[nf];
      }
      #pragma unroll
      for (int off = 8; off > 0; off >>= 1) {
        t0 += __shfl_down(t0, off);
        t1 += __shfl_down(t1, off);
      }
      if (fr == 0) {
        int p = row - b * 196;
        atomicAdd(&wgt[(b * 2 + 0) * 196 + p], t0);
        atomicAdd(&wgt[(b * 2 + 1) * 196 + p], t1);
      }
    }
  }
}

// ---------------- v_att[b,g,d] = sum_n softmax(wgt)[b,g,n] * Vt[b,n,d]
// softmax fused (waves 0/1); main loop vectorized: half8 loads (16B/lane),
// n-range split 4 ways across the 512 threads, LDS reduce (padded, no conflict).
__global__ __launch_bounds__(512) void k_vatt(const _Float16* __restrict__ Vt,
                                              const float* __restrict__ wgt,
                                              float* __restrict__ v_att) {
  __shared__ float a0s[196], a1s[196];
  __shared__ float red[2][3][128][9];
  int b = blockIdx.y;
  int tid = threadIdx.x;
  int wv = tid >> 6, lane = tid & 63;
  if (wv < 2) {
    const float* wr = wgt + ((size_t)b * 2 + wv) * 196;
    float v[4];
    #pragma unroll
    for (int i = 0; i < 4; ++i) {
      int n = lane + i * 64;
      v[i] = (n < 196) ? wr[n] : -1e30f;
    }
    float mx = fmaxf(fmaxf(v[0], v[1]), fmaxf(v[2], v[3]));
    #pragma unroll
    for (int off = 32; off > 0; off >>= 1) mx = fmaxf(mx, __shfl_xor(mx, off));
    float s = 0.f;
    #pragma unroll
    for (int i = 0; i < 4; ++i) {
      int n = lane + i * 64;
      float e = (n < 196) ? __expf(v[i] - mx) : 0.f;
      v[i] = e;
      s += e;
    }
    #pragma unroll
    for (int off = 32; off > 0; off >>= 1) s += __shfl_xor(s, off);
    float inv = 1.f / s;
    float* dst = wv ? a1s : a0s;
    #pragma unroll
    for (int i = 0; i < 4; ++i) {
      int n = lane + i * 64;
      if (n < 196) dst[n] = v[i] * inv;
    }
  }
  __syncthreads();
  int nc = tid >> 7;                 // 0..3: n-chunk
  int dl = tid & 127;
  int d = blockIdx.x * 1024 + dl * 8;
  const _Float16* vp = Vt + (size_t)b * 196 * 2048 + d;
  float s0[8] = {}, s1[8] = {};
  for (int n = nc * 49; n < nc * 49 + 49; ++n) {
    half8 v = *(const half8*)(vp + (size_t)n * 2048);
    float a0 = a0s[n], a1 = a1s[n];
    #pragma unroll
    for (int j = 0; j < 8; ++j) {
      float f = (float)v[j];
      s0[j] += a0 * f;
      s1[j] += a1 * f;
    }
  }
  if (nc > 0) {
    #pragma unroll
    for (int j = 0; j < 8; ++j) {
      red[0][nc - 1][dl][j] = s0[j];
      red[1][nc - 1][dl][j] = s1[j];
    }
  }
  __syncthreads();
  if (nc == 0) {
    #pragma unroll
    for (int c = 0; c < 3; ++c)
      #pragma unroll
      for (int j = 0; j < 8; ++j) {
        s0[j] += red[0][c][dl][j];
        s1[j] += red[1][c][dl][j];
      }
    #pragma unroll
    for (int j = 0; j < 8; ++j) {
      v_att[((size_t)b * 2 + 0) * 2048 + d + j] = s0[j];
      v_att[((size_t)b * 2 + 1) * 2048 + d + j] = s1[j];
    }
  }
}

// ---------------- merged Q-branch skinny: xq (N=1200,W=Wq_att) + q_fus (N=2400,W=Wq_fus)
// A = input_q [64][2400]; P layout [s][64][3600]: cols 0..1199 xq, 1200..3599 q_fus
__global__ __launch_bounds__(256) void k_skinnyQ(const float* __restrict__ q,
                                                 const float* __restrict__ Wa,
                                                 const float* __restrict__ Wf,
                                                 int S, float* __restrict__ P) {
  __shared__ __align__(16) float As[32][64];
  __shared__ __align__(16) float Ws2[32][64];
  int tid = threadIdx.x;
  int x = blockIdx.x;              // 0..56
  int s = blockIdx.y;
  bool f = x >= 19;
  const float* W = f ? Wf : Wa;
  int nt0 = f ? (x - 19) * 64 : x * 64;
  int N = f ? 2400 : 1200;
  int colBase = f ? 1200 : 0;
  const int K = 2400;
  int tiles = K >> 5;              // 75
  int t0 = (s * tiles) / S;
  int t1 = ((s + 1) * tiles) / S;
  int tx = tid & 15, ty = tid >> 4;
  int lm = tid >> 2;
  int lk = (tid & 3) * 8;
  const float* Ab = q + (size_t)lm * K;
  int ng = nt0 + lm;
  const float* Wb = W + (size_t)ng * K;
  bool wok = ng < N;
  float acc[4][4] = {};
  for (int t = t0; t < t1; ++t) {
    int k0 = t * 32;
    __syncthreads();
    #pragma unroll
    for (int j = 0; j < 8; ++j) As[lk + j][lm] = Ab[k0 + lk + j];
    #pragma unroll
    for (int j = 0; j < 8; ++j) Ws2[lk + j][lm] = wok ? Wb[k0 + lk + j] : 0.0f;
    __syncthreads();
    #pragma unroll
    for (int kk = 0; kk < 32; ++kk) {
      f32x4 a = *(const f32x4*)&As[kk][ty * 4];
      f32x4 wv = *(const f32x4*)&Ws2[kk][tx * 4];
      #pragma unroll
      for (int i = 0; i < 4; ++i)
        #pragma unroll
        for (int j = 0; j < 4; ++j) acc[i][j] += a[i] * wv[j];
    }
  }
  #pragma unroll
  for (int i = 0; i < 4; ++i) {
    int m = ty * 4 + i;
    #pragma unroll
    for (int j = 0; j < 4; ++j) {
      int nl = nt0 + tx * 4 + j;
      if (nl < N) P[((size_t)s * 64 + m) * 3600 + colBase + nl] = acc[i][j];
    }
  }
}

// ---------------- combineQ: xq and q_fus from merged partials
__global__ __launch_bounds__(256) void k_combineQ(const float* __restrict__ P, int S,
                                                  const float* __restrict__ bq_att,
                                                  const float* __restrict__ bq_fus,
                                                  float* __restrict__ xq,
                                                  float* __restrict__ q_fus) {
  int i = blockIdx.x * 256 + threadIdx.x;  // < 230400
  if (i >= 230400) return;
  int row = i / 3600, col = i % 3600;
  float sum = 0.f;
  for (int ss = 0; ss < S; ++ss) sum += P[(size_t)ss * 230400 + i];
  if (col < 1200) xq[row * 1200 + col] = tanh_fast(sum + bq_att[col]);
  else            q_fus[row * 2400 + col - 1200] = tanh_fast(sum + bq_fus[col - 1200]);
}

// ---------------- generic skinny GEMM, M=64, split-K partials
__global__ __launch_bounds__(256) void k_skinny(const float* __restrict__ A1,
                                                const float* __restrict__ A2,
                                                int lda, int strideAz,
                                                const float* __restrict__ W, long strideWz,
                                                int N, int K, int S,
                                                float* __restrict__ P, int ldp, int colOffZ) {
  __shared__ __align__(16) float As[32][64];
  __shared__ __align__(16) float Ws2[32][64];
  int tid = threadIdx.x;
  int z = blockIdx.z;
  int s = blockIdx.y;
  int nt0 = blockIdx.x * 64;
  int tiles = K >> 5;
  int t0 = (s * tiles) / S;
  int t1 = ((s + 1) * tiles) / S;
  int tx = tid & 15, ty = tid >> 4;
  int lm = tid >> 2;
  int lk = (tid & 3) * 8;
  const float* Ab = A1 + (size_t)z * strideAz + (size_t)lm * lda;
  const float* A2b = A2 ? (A2 + (size_t)z * strideAz + (size_t)lm * lda) : nullptr;
  int ng = nt0 + lm;
  const float* Wb = W + (size_t)z * strideWz + (size_t)ng * K;
  bool wok = ng < N;
  float acc[4][4] = {};
  for (int t = t0; t < t1; ++t) {
    int k0 = t * 32;
    __syncthreads();
    #pragma unroll
    for (int j = 0; j < 8; ++j) {
      float v = Ab[k0 + lk + j];
      if (A2b) v *= A2b[k0 + lk + j];
      As[lk + j][lm] = v;
    }
    #pragma unroll
    for (int j = 0; j < 8; ++j) Ws2[lk + j][lm] = wok ? Wb[k0 + lk + j] : 0.0f;
    __syncthreads();
    #pragma unroll
    for (int kk = 0; kk < 32; ++kk) {
      f32x4 a = *(const f32x4*)&As[kk][ty * 4];
      f32x4 wv = *(const f32x4*)&Ws2[kk][tx * 4];
      #pragma unroll
      for (int i = 0; i < 4; ++i)
        #pragma unroll
        for (int j = 0; j < 4; ++j) acc[i][j] += a[i] * wv[j];
    }
  }
  #pragma unroll
  for (int i = 0; i < 4; ++i) {
    int m = ty * 4 + i;
    #pragma unroll
    for (int j = 0; j < 4; ++j) {
      int nl = nt0 + tx * 4 + j;
      if (nl < N) P[((size_t)s * 64 + m) * ldp + z * colOffZ + nl] = acc[i][j];
    }
  }
}

// ---------------- combineVh: h = tanh(sum + bv_fus) * q_fus  (fused Hadamard)
__global__ __launch_bounds__(256) void k_combineVh(const float* __restrict__ P, int S,
                                                   const float* __restrict__ bv_fus,
                                                   const float* __restrict__ q_fus,
                                                   float* __restrict__ h) {
  int i = blockIdx.x * 256 + threadIdx.x;  // < 153600
  if (i >= 153600) return;
  int col = i % 2400;
  float sum = bv_fus[col];
  for (int ss = 0; ss < S; ++ss) sum += P[(size_t)ss * 153600 + i];
  h[i] = tanh_fast(sum) * q_fus[i];
}

// ---------------- combine: out[i] = sum_s P[s][i] + bias[i%ldp]
__global__ __launch_bounds__(256) void k_combine(const float* __restrict__ P, int S, int ldp,
                                                 const float* __restrict__ bias,
                                                 float* __restrict__ out, int total) {
  int i = blockIdx.x * 256 + threadIdx.x;
  if (i >= total) return;
  float sum = bias[i % ldp];
  for (int ss = 0; ss < S; ++ss) sum += P[(size_t)ss * total + i];
  out[i] = sum;
}

extern "C" void kernel_launch(void* const* d_in, const int* in_sizes, int n_in,
                              void* d_out, int out_size, void* d_ws, size_t ws_size,
                              hipStream_t stream) {
  const float* input_q = (const float*)d_in[0];
  const float* input_v = (const float*)d_in[1];
  const float* Wv_att  = (const float*)d_in[2];
  const float* bv_att  = (const float*)d_in[3];
  const float* Wq_att  = (const float*)d_in[4];
  const float* bq_att  = (const float*)d_in[5];
  const float* Watt    = (const float*)d_in[6];
  const float* batt    = (const float*)d_in[7];
  const float* Wv_fus  = (const float*)d_in[8];
  const float* bv_fus  = (const float*)d_in[9];
  const float* Wq_fus  = (const float*)d_in[10];
  const float* bq_fus  = (const float*)d_in[11];
  const float* Wc      = (const float*)d_in[12];
  const float* bc      = (const float*)d_in[13];
  float* out = (float*)d_out;

  char* ws = (char*)d_ws;
  _Float16* Vt   = (_Float16*)ws; ws += 51380224;   // 64*196*2048 fp16
  _Float16* Wh   = (_Float16*)ws; ws += 5242880;    // 1280*2048 fp16
  float* xq      = (float*)ws;    ws += 307200;     // 64*1200 f32
  float* v_att   = (float*)ws;    ws += 1048576;    // 64*2*2048 f32
  float* v_fus   = (float*)ws;    ws += 614400;     // 64*2400 f32 (becomes h)
  float* q_fus   = (float*)ws;    ws += 614400;     // 64*2400 f32
  float* P       = (float*)ws;    ws += 14745600;   // 3,686,400 f32 partials

  float* x_out   = out;            // [64][3000]
  float* wgt_out = out + 192000;   // [64][2][196]

  const int S = 16;

  // stage conversions + wgt init
  k_transpose_v<<<dim3(4, 32, 64), dim3(256), 0, stream>>>(input_v, Vt);
  k_prep<<<dim3(10240), dim3(256), 0, stream>>>(Wv_att, Wh, batt, wgt_out);

  // merged Q-branch: xq + q_fus
  k_skinnyQ<<<dim3(57, S), dim3(256), 0, stream>>>(input_q, Wq_att, Wq_fus, S, P);
  k_combineQ<<<dim3(900), dim3(256), 0, stream>>>(P, S, bq_att, bq_fus, xq, q_fus);

  // fused: xv-tanh-xq-tanh-Watt -> wgt (output 1); xatt never materialized
  k_gemm1<<<dim3(5, 49), dim3(512), 0, stream>>>(Vt, Wh, bv_att, xq, Watt, wgt_out);

  // softmax (fused) + v_att
  k_vatt<<<dim3(2, 64), dim3(512), 0, stream>>>(Vt, wgt_out, v_att);

  // v_fus partials, then h = tanh(v_fus)*q_fus
  k_skinny<<<dim3(19, S, 2), dim3(256), 0, stream>>>(v_att, nullptr, 4096, 2048,
                                                     Wv_fus, 1200L * 2048L, 1200, 2048, S, P, 2400, 1200);
  k_combineVh<<<dim3(600), dim3(256), 0, stream>>>(P, S, bv_fus, q_fus, v_fus);

  // x = h @ Wc^T + bc  (output 0)
  k_skinny<<<dim3(47, S, 1), dim3(256), 0, stream>>>(v_fus, nullptr, 2400, 0,
                                                     Wc, 0, 3000, 2400, S, P, 3000, 0);
  k_combine<<<dim3(750), dim3(256), 0, stream>>>(P, S, 3000, bc, x_out, 192000);
}

// Round 6
// 437.197 us; speedup vs baseline: 1.0255x; 1.0255x over previous
//
#include <hip/hip_runtime.h>
#include <hip/hip_fp16.h>

typedef _Float16 half8 __attribute__((ext_vector_type(8)));
typedef float f32x4 __attribute__((ext_vector_type(4)));

__device__ __forceinline__ float tanh_fast(float x) {
  float e = __expf(2.0f * x);
  return 1.0f - 2.0f / (e + 1.0f);
}

__device__ __forceinline__ void gload16(const _Float16* g, _Float16* l) {
  __builtin_amdgcn_global_load_lds((const __attribute__((address_space(1))) void*)g,
                                   (__attribute__((address_space(3))) void*)l,
                                   16, 0, 0);
}

// ---------------- transpose input_v [64][2048][196] f32 -> Vt [64][196][2048] fp16
__global__ __launch_bounds__(256) void k_transpose_v(const float* __restrict__ in,
                                                     _Float16* __restrict__ out) {
  __shared__ float t[64][65];
  int b = blockIdx.z;
  int c0 = blockIdx.y * 64;
  int p0 = blockIdx.x * 64;
  int tid = threadIdx.x;
  int pl = tid & 63;
  #pragma unroll
  for (int s = 0; s < 16; ++s) {
    int cl = (tid >> 6) + s * 4;
    int p = p0 + pl;
    t[cl][pl] = (p < 196) ? in[((size_t)b * 2048 + (c0 + cl)) * 196 + p] : 0.0f;
  }
  __syncthreads();
  int c8 = (tid & 7) * 8;
  #pragma unroll
  for (int s = 0; s < 2; ++s) {
    int p = p0 + (tid >> 3) + s * 32;
    if (p < 196) {
      half8 v;
      #pragma unroll
      for (int j = 0; j < 8; ++j) v[j] = (_Float16)t[c8 + j][(tid >> 3) + s * 32];
      *(half8*)(out + ((size_t)b * 196 + p) * 2048 + c0 + c8) = v;
    }
  }
}

// ---------------- prep: Wv_att f32 -> fp16 padded to 1280 rows; wgt init with batt
__global__ __launch_bounds__(256) void k_prep(const float* __restrict__ W,
                                              _Float16* __restrict__ Wh,
                                              const float* __restrict__ batt,
                                              float* __restrict__ wgt) {
  int i = blockIdx.x * 256 + threadIdx.x;  // < 1280*2048
  int n = i >> 11;
  Wh[i] = (n < 1200) ? (_Float16)W[i] : (_Float16)0.0f;
  if (i < 25088) wgt[i] = batt[(i / 196) & 1];
}

// ---------------- big MFMA GEMM v7: 256x256 tile, BK=64, 8 waves, 8-phase schedule.
// v6->v7: UN-SERIALIZE each phase. Removed: BAR1 (redundant: each wave's reads
// complete before its own MFMA (register dep) hence before the phase-end BAR;
// stage-writes only issue after the BAR that follows the last read of that
// buffer; vmcnt gates precede a BAR that precedes dependent reads) and ALL
// manual lgkmcnt drains (the lgkmcnt(0) full-drain forced LDS-read windows
// (256-768 cyc/CU) serial with the MFMA window (~620 cyc); the compiler's own
// per-dependency counted waits let the MFMA cluster start after the first
// fragments land and stream the rest concurrently). Reads emitted kk-major,
// B before A, so the first MFMA's operands arrive first.
// One s_barrier + compiler fence per phase; vmcnt(6) gates at ph4/ph8 only.
// Bijective XCD swizzle; zero-VALU ds addressing (v6); array-free epilogue.
__global__ __launch_bounds__(512, 2) void k_gemm1(const _Float16* __restrict__ A,
                                                  const _Float16* __restrict__ B,
                                                  const float* __restrict__ bias,
                                                  const float* __restrict__ xq,
                                                  const float* __restrict__ Watt,
                                                  float* __restrict__ wgt) {
  __shared__ __align__(16) _Float16 AS[2][256 * 64];
  __shared__ __align__(16) _Float16 BS[2][256 * 64];
  int tid = threadIdx.x;
  // bijective XCD swizzle: 245 wgs, 8 XCDs -> q=30, r=5
  int lin = blockIdx.y * 5 + blockIdx.x;
  int xcd = lin & 7;
  int loc = lin >> 3;
  int nw = (xcd < 5 ? xcd * 31 : 155 + (xcd - 5) * 30) + loc;
  int n0 = (nw % 5) * 256;     // 5 n-tiles (padded N=1280)
  int m0 = (nw / 5) * 256;     // 49 m-tiles, exact
  int lane = tid & 63;
  int wave = tid >> 6;
  int wm = (wave >> 2) * 128;  // 2 wave rows
  int wn = (wave & 3) * 64;    // 4 wave cols
  int fr = lane & 15;
  int fq = lane >> 4;

  // ---- ds_read lane indices (halfs): idx = row*64 + ((kk*4+fq)^(fr&7))*8,
  // with row = (wm|wn) + fr (row&7 == fr&7 -> swizzle term lane-constant).
  int aIdx[2], bIdx[2];
  #pragma unroll
  for (int kk = 0; kk < 2; ++kk) {
    int sw = (((kk * 4 + fq) ^ (fr & 7)) << 3);
    aIdx[kk] = (wm + fr) * 64 + sw;
    bIdx[kk] = (wn + fr) * 64 + sw;
  }

  // ---- staging addressing: instr (h,j) covers 64 rows x 8 chunks; lane ->
  // row += lane>>3, chunk (lane&7) swizzled by row&7 (= lane>>3).
  int lr = lane >> 3;
  int swz8 = ((lane & 7) ^ lr) << 3;
  const _Float16* aSrc[2][2];
  const _Float16* bSrc[2][2];
  int aDst[2][2], bDst[2][2];
  #pragma unroll
  for (int h = 0; h < 2; ++h)
    #pragma unroll
    for (int j = 0; j < 2; ++j) {
      int ra = j * 128 + h * 64 + wave * 8;                  // A block-row
      aSrc[h][j] = A + (size_t)(m0 + ra + lr) * 2048 + swz8;
      aDst[h][j] = ra * 64;
      int rb = (j * 2 + (wave >> 2)) * 64 + h * 32 + (wave & 3) * 8;  // B block-row
      bSrc[h][j] = B + (size_t)(n0 + rb + lr) * 2048 + swz8;
      bDst[h][j] = rb * 64;
    }

  f32x4 acc[8][4];
  #pragma unroll
  for (int i = 0; i < 8; ++i)
    #pragma unroll
    for (int j = 0; j < 4; ++j) acc[i][j] = (f32x4){0.f, 0.f, 0.f, 0.f};

  // off = compile-time halfs offset relative to current iteration base
  auto stA = [&](int buf, int h, int off) {
    gload16(aSrc[h][0] + off, &AS[buf][aDst[h][0]]);
    gload16(aSrc[h][1] + off, &AS[buf][aDst[h][1]]);
  };
  auto stB = [&](int buf, int h, int off) {
    gload16(bSrc[h][0] + off, &BS[buf][bDst[h][0]]);
    gload16(bSrc[h][1] + off, &BS[buf][bDst[h][1]]);
  };
  // kk-major emission: the kk=0 fragments (consumed first) arrive first.
  auto dsA = [&](int buf, int mh, half8 (&a)[4][2]) {
    #pragma unroll
    for (int kk = 0; kk < 2; ++kk)
      #pragma unroll
      for (int mt = 0; mt < 4; ++mt)
        a[mt][kk] = *(const half8*)&AS[0][aIdx[kk] + (buf * 16384 + mh * 4096 + mt * 1024)];
  };
  auto dsB = [&](int buf, int nh, half8 (&b)[2][2]) {
    #pragma unroll
    for (int kk = 0; kk < 2; ++kk)
      #pragma unroll
      for (int nt = 0; nt < 2; ++nt)
        b[nt][kk] = *(const half8*)&BS[0][bIdx[kk] + (buf * 16384 + nh * 2048 + nt * 1024)];
  };
  auto mma = [&](half8 (&a)[4][2], half8 (&b)[2][2], int mh, int nh) {
    __builtin_amdgcn_s_setprio(1);
    #pragma unroll
    for (int kk = 0; kk < 2; ++kk)          // kk outermost: 8 independent MFMAs
      #pragma unroll
      for (int mt = 0; mt < 4; ++mt)
        #pragma unroll
        for (int nt = 0; nt < 2; ++nt)
          acc[mh * 4 + mt][nh * 2 + nt] = __builtin_amdgcn_mfma_f32_16x16x32_f16(
              a[mt][kk], b[nt][kk], acc[mh * 4 + mt][nh * 2 + nt], 0, 0, 0);
    __builtin_amdgcn_s_setprio(0);
  };

#define BAR() __builtin_amdgcn_s_barrier()
#define FENCE() asm volatile("" ::: "memory")

  // prologue: tile0 -> buf0 complete (oldest 8), tile1 -> buf1 {Aa,B0,B1} (6)
  stA(0, 0, 0); stB(0, 0, 0); stB(0, 1, 0); stA(0, 1, 0);
  stA(1, 0, 64); stB(1, 0, 64); stB(1, 1, 64);
  asm volatile("s_waitcnt vmcnt(6)" ::: "memory");
  BAR();
  FENCE();

  half8 a[4][2], b0[2][2], b1[2][2];
  for (int i = 0; i < 16; ++i) {
    const bool nl = (i < 15);
    // ---- ph1: Q(mh0,nh0) buf0 | stage buf1.Abeta (tile 2i+1)
    dsB(0, 0, b0); dsA(0, 0, a);
    stA(1, 1, 64);
    mma(a, b0, 0, 0);
    BAR(); FENCE();
    // ---- ph2: Q(mh0,nh1) | stage buf0.Aalpha (tile 2i+2)
    dsB(0, 1, b1);
    if (nl) stA(0, 0, 128);
    mma(a, b1, 0, 1);
    BAR(); FENCE();
    // ---- ph3: Q(mh1,nh1) | stage buf0.B0
    dsA(0, 1, a);
    if (nl) stB(0, 0, 128);
    mma(a, b1, 1, 1);
    BAR(); FENCE();
    // ---- ph4: Q(mh1,nh0) (b0 from regs) | stage buf0.B1 | vmcnt gate for buf1
    if (nl) {
      stB(0, 1, 128);
      asm volatile("s_waitcnt vmcnt(6)" ::: "memory");
    } else {
      asm volatile("s_waitcnt vmcnt(0)" ::: "memory");
    }
    mma(a, b0, 1, 0);
    BAR(); FENCE();
    // ---- ph5: Q(mh0,nh0) buf1 | stage buf0.Abeta
    dsB(1, 0, b0); dsA(1, 0, a);
    if (nl) stA(0, 1, 128);
    mma(a, b0, 0, 0);
    BAR(); FENCE();
    // ---- ph6: Q(mh0,nh1) | stage buf1.Aalpha (tile 2i+3)
    dsB(1, 1, b1);
    if (nl) stA(1, 0, 192);
    mma(a, b1, 0, 1);
    BAR(); FENCE();
    // ---- ph7: Q(mh1,nh1) | stage buf1.B0
    dsA(1, 1, a);
    if (nl) stB(1, 0, 192);
    mma(a, b1, 1, 1);
    BAR(); FENCE();
    // ---- ph8: Q(mh1,nh0) | stage buf1.B1 | vmcnt gate for buf0
    if (nl) {
      stB(1, 1, 192);
      asm volatile("s_waitcnt vmcnt(6)" ::: "memory");
    }
    mma(a, b0, 1, 0);
    BAR(); FENCE();
    // ---- advance staging pointers by 2 K-tiles (128 halfs)
    #pragma unroll
    for (int h = 0; h < 2; ++h)
      #pragma unroll
      for (int j = 0; j < 2; ++j) { aSrc[h][j] += 128; bSrc[h][j] += 128; }
  }
#undef BAR
#undef FENCE

  // ---- fused epilogue (array-free): xa = tanh(tanh(acc+bias)*xq); wgt += xa*Watt
  float bcol[4], wa0c[4], wa1c[4], xqv[4];
  int colv[4]; bool okv[4];
  #pragma unroll
  for (int nf = 0; nf < 4; ++nf) {
    int col = n0 + wn + (nf >> 1) * 32 + (nf & 1) * 16 + fr;
    bool ok = col < 1200;
    colv[nf] = col; okv[nf] = ok;
    bcol[nf] = ok ? bias[col] : 0.f;
    wa0c[nf] = ok ? Watt[col] : 0.f;
    wa1c[nf] = ok ? Watt[1200 + col] : 0.f;
    xqv[nf] = 0.f;
  }
  int bprev = -1;
  #pragma unroll
  for (int mf = 0; mf < 8; ++mf) {
    #pragma unroll
    for (int r = 0; r < 4; ++r) {
      int row = m0 + wm + (mf >> 2) * 64 + (mf & 3) * 16 + fq * 4 + r;
      int b = row / 196;
      if (b != bprev) {
        bprev = b;
        #pragma unroll
        for (int nf = 0; nf < 4; ++nf)
          xqv[nf] = okv[nf] ? xq[b * 1200 + colv[nf]] : 0.f;
      }
      float t0 = 0.f, t1 = 0.f;
      #pragma unroll
      for (int nf = 0; nf < 4; ++nf) {
        float xv = tanh_fast(acc[mf][nf][r] + bcol[nf]);
        float xa = tanh_fast(xv * xqv[nf]);
        t0 += xa * wa0c[nf];
        t1 += xa * wa1c[nf];
      }
      #pragma unroll
      for (int off = 8; off > 0; off >>= 1) {
        t0 += __shfl_down(t0, off);
        t1 += __shfl_down(t1, off);
      }
      if (fr == 0) {
        int p = row - b * 196;
        atomicAdd(&wgt[(b * 2 + 0) * 196 + p], t0);
        atomicAdd(&wgt[(b * 2 + 1) * 196 + p], t1);
      }
    }
  }
}

// ---------------- v_att[b,g,d] = sum_n softmax(wgt)[b,g,n] * Vt[b,n,d]
// v7: grid 512 blocks (was 128 -> half the GPU idle). 256 threads: 32 d-octets
// (half8) x 8 n-chunks; softmax recomputed per block (cheap); padded LDS reduce.
__global__ __launch_bounds__(256) void k_vatt(const _Float16* __restrict__ Vt,
                                              const float* __restrict__ wgt,
                                              float* __restrict__ v_att) {
  __shared__ float a0s[196], a1s[196];
  __shared__ float red[2][7][32][9];
  int b = blockIdx.y;
  int tid = threadIdx.x;
  int wv = tid >> 6, lane = tid & 63;
  if (wv < 2) {
    const float* wr = wgt + ((size_t)b * 2 + wv) * 196;
    float v[4];
    #pragma unroll
    for (int i = 0; i < 4; ++i) {
      int n = lane + i * 64;
      v[i] = (n < 196) ? wr[n] : -1e30f;
    }
    float mx = fmaxf(fmaxf(v[0], v[1]), fmaxf(v[2], v[3]));
    #pragma unroll
    for (int off = 32; off > 0; off >>= 1) mx = fmaxf(mx, __shfl_xor(mx, off));
    float s = 0.f;
    #pragma unroll
    for (int i = 0; i < 4; ++i) {
      int n = lane + i * 64;
      float e = (n < 196) ? __expf(v[i] - mx) : 0.f;
      v[i] = e;
      s += e;
    }
    #pragma unroll
    for (int off = 32; off > 0; off >>= 1) s += __shfl_xor(s, off);
    float inv = 1.f / s;
    float* dst = wv ? a1s : a0s;
    #pragma unroll
    for (int i = 0; i < 4; ++i) {
      int n = lane + i * 64;
      if (n < 196) dst[n] = v[i] * inv;
    }
  }
  __syncthreads();
  int dg = tid & 31;                 // d-octet within block
  int nc = tid >> 5;                 // 0..7: n-chunk
  int d = blockIdx.x * 256 + dg * 8;
  const _Float16* vp = Vt + (size_t)b * 196 * 2048 + d;
  int nA = (nc * 196) >> 3, nB = ((nc + 1) * 196) >> 3;
  float s0[8] = {}, s1[8] = {};
  for (int n = nA; n < nB; ++n) {
    half8 v = *(const half8*)(vp + (size_t)n * 2048);
    float a0 = a0s[n], a1 = a1s[n];
    #pragma unroll
    for (int j = 0; j < 8; ++j) {
      float f = (float)v[j];
      s0[j] += a0 * f;
      s1[j] += a1 * f;
    }
  }
  if (nc > 0) {
    #pragma unroll
    for (int j = 0; j < 8; ++j) {
      red[0][nc - 1][dg][j] = s0[j];
      red[1][nc - 1][dg][j] = s1[j];
    }
  }
  __syncthreads();
  if (nc == 0) {
    #pragma unroll
    for (int c = 0; c < 7; ++c)
      #pragma unroll
      for (int j = 0; j < 8; ++j) {
        s0[j] += red[0][c][dg][j];
        s1[j] += red[1][c][dg][j];
      }
    #pragma unroll
    for (int j = 0; j < 8; ++j) {
      v_att[((size_t)b * 2 + 0) * 2048 + d + j] = s0[j];
      v_att[((size_t)b * 2 + 1) * 2048 + d + j] = s1[j];
    }
  }
}

// ---------------- merged Q-branch skinny: xq (N=1200,W=Wq_att) + q_fus (N=2400,W=Wq_fus)
// A = input_q [64][2400]; P layout [s][64][3600]: cols 0..1199 xq, 1200..3599 q_fus
__global__ __launch_bounds__(256) void k_skinnyQ(const float* __restrict__ q,
                                                 const float* __restrict__ Wa,
                                                 const float* __restrict__ Wf,
                                                 int S, float* __restrict__ P) {
  __shared__ __align__(16) float As[32][64];
  __shared__ __align__(16) float Ws2[32][64];
  int tid = threadIdx.x;
  int x = blockIdx.x;              // 0..56
  int s = blockIdx.y;
  bool f = x >= 19;
  const float* W = f ? Wf : Wa;
  int nt0 = f ? (x - 19) * 64 : x * 64;
  int N = f ? 2400 : 1200;
  int colBase = f ? 1200 : 0;
  const int K = 2400;
  int tiles = K >> 5;              // 75
  int t0 = (s * tiles) / S;
  int t1 = ((s + 1) * tiles) / S;
  int tx = tid & 15, ty = tid >> 4;
  int lm = tid >> 2;
  int lk = (tid & 3) * 8;
  const float* Ab = q + (size_t)lm * K;
  int ng = nt0 + lm;
  const float* Wb = W + (size_t)ng * K;
  bool wok = ng < N;
  float acc[4][4] = {};
  for (int t = t0; t < t1; ++t) {
    int k0 = t * 32;
    __syncthreads();
    #pragma unroll
    for (int j = 0; j < 8; ++j) As[lk + j][lm] = Ab[k0 + lk + j];
    #pragma unroll
    for (int j = 0; j < 8; ++j) Ws2[lk + j][lm] = wok ? Wb[k0 + lk + j] : 0.0f;
    __syncthreads();
    #pragma unroll
    for (int kk = 0; kk < 32; ++kk) {
      f32x4 a = *(const f32x4*)&As[kk][ty * 4];
      f32x4 wv = *(const f32x4*)&Ws2[kk][tx * 4];
      #pragma unroll
      for (int i = 0; i < 4; ++i)
        #pragma unroll
        for (int j = 0; j < 4; ++j) acc[i][j] += a[i] * wv[j];
    }
  }
  #pragma unroll
  for (int i = 0; i < 4; ++i) {
    int m = ty * 4 + i;
    #pragma unroll
    for (int j = 0; j < 4; ++j) {
      int nl = nt0 + tx * 4 + j;
      if (nl < N) P[((size_t)s * 64 + m) * 3600 + colBase + nl] = acc[i][j];
    }
  }
}

// ---------------- combineQ: xq and q_fus from merged partials
__global__ __launch_bounds__(256) void k_combineQ(const float* __restrict__ P, int S,
                                                  const float* __restrict__ bq_att,
                                                  const float* __restrict__ bq_fus,
                                                  float* __restrict__ xq,
                                                  float* __restrict__ q_fus) {
  int i = blockIdx.x * 256 + threadIdx.x;  // < 230400
  if (i >= 230400) return;
  int row = i / 3600, col = i % 3600;
  float sum = 0.f;
  for (int ss = 0; ss < S; ++ss) sum += P[(size_t)ss * 230400 + i];
  if (col < 1200) xq[row * 1200 + col] = tanh_fast(sum + bq_att[col]);
  else            q_fus[row * 2400 + col - 1200] = tanh_fast(sum + bq_fus[col - 1200]);
}

// ---------------- generic skinny GEMM, M=64, split-K partials
__global__ __launch_bounds__(256) void k_skinny(const float* __restrict__ A1,
                                                const float* __restrict__ A2,
                                                int lda, int strideAz,
                                                const float* __restrict__ W, long strideWz,
                                                int N, int K, int S,
                                                float* __restrict__ P, int ldp, int colOffZ) {
  __shared__ __align__(16) float As[32][64];
  __shared__ __align__(16) float Ws2[32][64];
  int tid = threadIdx.x;
  int z = blockIdx.z;
  int s = blockIdx.y;
  int nt0 = blockIdx.x * 64;
  int tiles = K >> 5;
  int t0 = (s * tiles) / S;
  int t1 = ((s + 1) * tiles) / S;
  int tx = tid & 15, ty = tid >> 4;
  int lm = tid >> 2;
  int lk = (tid & 3) * 8;
  const float* Ab = A1 + (size_t)z * strideAz + (size_t)lm * lda;
  const float* A2b = A2 ? (A2 + (size_t)z * strideAz + (size_t)lm * lda) : nullptr;
  int ng = nt0 + lm;
  const float* Wb = W + (size_t)z * strideWz + (size_t)ng * K;
  bool wok = ng < N;
  float acc[4][4] = {};
  for (int t = t0; t < t1; ++t) {
    int k0 = t * 32;
    __syncthreads();
    #pragma unroll
    for (int j = 0; j < 8; ++j) {
      float v = Ab[k0 + lk + j];
      if (A2b) v *= A2b[k0 + lk + j];
      As[lk + j][lm] = v;
    }
    #pragma unroll
    for (int j = 0; j < 8; ++j) Ws2[lk + j][lm] = wok ? Wb[k0 + lk + j] : 0.0f;
    __syncthreads();
    #pragma unroll
    for (int kk = 0; kk < 32; ++kk) {
      f32x4 a = *(const f32x4*)&As[kk][ty * 4];
      f32x4 wv = *(const f32x4*)&Ws2[kk][tx * 4];
      #pragma unroll
      for (int i = 0; i < 4; ++i)
        #pragma unroll
        for (int j = 0; j < 4; ++j) acc[i][j] += a[i] * wv[j];
    }
  }
  #pragma unroll
  for (int i = 0; i < 4; ++i) {
    int m = ty * 4 + i;
    #pragma unroll
    for (int j = 0; j < 4; ++j) {
      int nl = nt0 + tx * 4 + j;
      if (nl < N) P[((size_t)s * 64 + m) * ldp + z * colOffZ + nl] = acc[i][j];
    }
  }
}

// ---------------- combineVh: h = tanh(sum + bv_fus) * q_fus  (fused Hadamard)
__global__ __launch_bounds__(256) void k_combineVh(const float* __restrict__ P, int S,
                                                   const float* __restrict__ bv_fus,
                                                   const float* __restrict__ q_fus,
                                                   float* __restrict__ h) {
  int i = blockIdx.x * 256 + threadIdx.x;  // < 153600
  if (i >= 153600) return;
  int col = i % 2400;
  float sum = bv_fus[col];
  for (int ss = 0; ss < S; ++ss) sum += P[(size_t)ss * 153600 + i];
  h[i] = tanh_fast(sum) * q_fus[i];
}

// ---------------- combine: out[i] = sum_s P[s][i] + bias[i%ldp]
__global__ __launch_bounds__(256) void k_combine(const float* __restrict__ P, int S, int ldp,
                                                 const float* __restrict__ bias,
                                                 float* __restrict__ out, int total) {
  int i = blockIdx.x * 256 + threadIdx.x;
  if (i >= total) return;
  float sum = bias[i % ldp];
  for (int ss = 0; ss < S; ++ss) sum += P[(size_t)ss * total + i];
  out[i] = sum;
}

extern "C" void kernel_launch(void* const* d_in, const int* in_sizes, int n_in,
                              void* d_out, int out_size, void* d_ws, size_t ws_size,
                              hipStream_t stream) {
  const float* input_q = (const float*)d_in[0];
  const float* input_v = (const float*)d_in[1];
  const float* Wv_att  = (const float*)d_in[2];
  const float* bv_att  = (const float*)d_in[3];
  const float* Wq_att  = (const float*)d_in[4];
  const float* bq_att  = (const float*)d_in[5];
  const float* Watt    = (const float*)d_in[6];
  const float* batt    = (const float*)d_in[7];
  const float* Wv_fus  = (const float*)d_in[8];
  const float* bv_fus  = (const float*)d_in[9];
  const float* Wq_fus  = (const float*)d_in[10];
  const float* bq_fus  = (const float*)d_in[11];
  const float* Wc      = (const float*)d_in[12];
  const float* bc      = (const float*)d_in[13];
  float* out = (float*)d_out;

  char* ws = (char*)d_ws;
  _Float16* Vt   = (_Float16*)ws; ws += 51380224;   // 64*196*2048 fp16
  _Float16* Wh   = (_Float16*)ws; ws += 5242880;    // 1280*2048 fp16
  float* xq      = (float*)ws;    ws += 307200;     // 64*1200 f32
  float* v_att   = (float*)ws;    ws += 1048576;    // 64*2*2048 f32
  float* v_fus   = (float*)ws;    ws += 614400;     // 64*2400 f32 (becomes h)
  float* q_fus   = (float*)ws;    ws += 614400;     // 64*2400 f32
  float* P       = (float*)ws;    ws += 14745600;   // 3,686,400 f32 partials

  float* x_out   = out;            // [64][3000]
  float* wgt_out = out + 192000;   // [64][2][196]

  const int S = 16;

  // stage conversions + wgt init
  k_transpose_v<<<dim3(4, 32, 64), dim3(256), 0, stream>>>(input_v, Vt);
  k_prep<<<dim3(10240), dim3(256), 0, stream>>>(Wv_att, Wh, batt, wgt_out);

  // merged Q-branch: xq + q_fus
  k_skinnyQ<<<dim3(57, S), dim3(256), 0, stream>>>(input_q, Wq_att, Wq_fus, S, P);
  k_combineQ<<<dim3(900), dim3(256), 0, stream>>>(P, S, bq_att, bq_fus, xq, q_fus);

  // fused: xv-tanh-xq-tanh-Watt -> wgt (output 1); xatt never materialized
  k_gemm1<<<dim3(5, 49), dim3(512), 0, stream>>>(Vt, Wh, bv_att, xq, Watt, wgt_out);

  // softmax (fused) + v_att
  k_vatt<<<dim3(8, 64), dim3(256), 0, stream>>>(Vt, wgt_out, v_att);

  // v_fus partials, then h = tanh(v_fus)*q_fus
  k_skinny<<<dim3(19, S, 2), dim3(256), 0, stream>>>(v_att, nullptr, 4096, 2048,
                                                     Wv_fus, 1200L * 2048L, 1200, 2048, S, P, 2400, 1200);
  k_combineVh<<<dim3(600), dim3(256), 0, stream>>>(P, S, bv_fus, q_fus, v_fus);

  // x = h @ Wc^T + bc  (output 0)
  k_skinny<<<dim3(47, S, 1), dim3(256), 0, stream>>>(v_fus, nullptr, 2400, 0,
                                                     Wc, 0, 3000, 2400, S, P, 3000, 0);
  k_combine<<<dim3(750), dim3(256), 0, stream>>>(P, S, 3000, bc, x_out, 192000);
}